// Round 5
// baseline (995.210 us; speedup 1.0000x reference)
//
#include <hip/hip_runtime.h>
#include <hip/hip_bf16.h>
#include <cmath>

typedef __attribute__((ext_vector_type(8))) short s16x8;
typedef __attribute__((ext_vector_type(8))) __bf16 bf16x8;
typedef __attribute__((ext_vector_type(4))) float f32x4;

__device__ __forceinline__ float b2f(short u) {
  union { unsigned int u32; float f; } c;
  c.u32 = ((unsigned int)(unsigned short)u) << 16;
  return c.f;
}
__device__ __forceinline__ short f2b(float f) {
  __hip_bfloat16 h = __float2bfloat16(f);
  return *reinterpret_cast<short*>(&h);
}

__device__ __forceinline__ f32x4 mfma16(bf16x8 a, bf16x8 b, f32x4 c) {
  return __builtin_amdgcn_mfma_f32_16x16x32_bf16(a, b, c, 0, 0, 0);
}

// ---------------------------------------------------------------- f32 -> bf16
__global__ __launch_bounds__(256) void conv_k(const float* __restrict__ in,
                                              short* __restrict__ out, int n) {
  int stride = gridDim.x << 8;
  for (int i = (blockIdx.x << 8) + threadIdx.x; i < n; i += stride)
    out[i] = f2b(in[i]);
}

// ---------------------------------------------------------------- pos table
// rows 0..2046: [sin(pos*inv_c) | cos(pos*inv_c)], pos = 1023 - row; row 2047 = 0
__global__ __launch_bounds__(256) void pos_k(short* __restrict__ out) {
  int row = blockIdx.x;
  int t = threadIdx.x;
#pragma unroll
  for (int i = 0; i < 4; ++i) {
    int c = t + (i << 8);
    float val = 0.f;
    if (row < 2047) {
      int f = (c < 512) ? c : c - 512;
      float inv = expf(-(float)f * (float)(9.210340371976184 / 512.0));
      float ang = (float)(1023 - row) * inv;
      val = (c < 512) ? sinf(ang) : cosf(ang);
    }
    out[row * 1024 + c] = f2b(val);
  }
}

// ---------------------------------------------------------------- layernorm (f32 in, bf16 out)
__global__ __launch_bounds__(256) void ln_k(const float* __restrict__ in,
                                            const float* __restrict__ g,
                                            const float* __restrict__ bb,
                                            short* __restrict__ out) {
  int row = blockIdx.x;
  int t = threadIdx.x;
  float v[4];
#pragma unroll
  for (int i = 0; i < 4; ++i) v[i] = in[row * 1024 + t + (i << 8)];
  __shared__ float red1[4], red2[4];
  float s = v[0] + v[1] + v[2] + v[3];
#pragma unroll
  for (int m = 1; m < 64; m <<= 1) s += __shfl_xor(s, m);
  if ((t & 63) == 0) red1[t >> 6] = s;
  __syncthreads();
  float mean = (red1[0] + red1[1] + red1[2] + red1[3]) * (1.f / 1024.f);
  float d2 = 0.f;
#pragma unroll
  for (int i = 0; i < 4; ++i) { float d = v[i] - mean; d2 += d * d; }
#pragma unroll
  for (int m = 1; m < 64; m <<= 1) d2 += __shfl_xor(d2, m);
  if ((t & 63) == 0) red2[t >> 6] = d2;
  __syncthreads();
  float var = (red2[0] + red2[1] + red2[2] + red2[3]) * (1.f / 1024.f);
  float rstd = rsqrtf(var + 1e-5f);
#pragma unroll
  for (int i = 0; i < 4; ++i) {
    int c = t + (i << 8);
    out[row * 1024 + c] = f2b((v[i] - mean) * rstd * g[c] + bb[c]);
  }
}

// ---------------------------------------------------------------- MFMA GEMM
// C[M=2048, N=1024] = A[2048,1024] @ B[1024,1024], A,B bf16 row-major.
// EP 0: bf16 row-major out; EP 1: qkv layout [B,H,L,DH]; EP 2: f32 out = acc + resid(f32)
#define GD 1024
template <int EP>
__global__ __launch_bounds__(256) void gemm_k(const short* __restrict__ A,
                                              const short* __restrict__ B,
                                              void* __restrict__ outp,
                                              const float* __restrict__ resid) {
  __shared__ __align__(16) short lA[64 * 40];
  __shared__ __align__(16) short lB[64 * 40];
  const int tid = threadIdx.x;
  const int wave = tid >> 6, lane = tid & 63;
  const int wr = wave >> 1, wc = wave & 1;
  const int m0 = blockIdx.y * 64, n0 = blockIdx.x * 64;
  f32x4 acc[2][2] = {};
  const int ar = tid >> 2, ak = (tid & 3) << 3;
  const int bk = tid >> 3, bn = (tid & 7) << 3;
  const int k8 = (lane >> 4) << 3;
  const int rA0 = wr * 32 + (lane & 15);
  const int cB0 = wc * 32 + (lane & 15);
  for (int kt = 0; kt < GD; kt += 32) {
    *(bf16x8*)&lA[ar * 40 + ak] = *(const bf16x8*)&A[(m0 + ar) * GD + kt + ak];
    s16x8 bv = *(const s16x8*)&B[(kt + bk) * GD + n0 + bn];
#pragma unroll
    for (int i = 0; i < 8; ++i) lB[(bn + i) * 40 + bk] = bv[i];
    __syncthreads();
    bf16x8 a0 = *(bf16x8*)&lA[rA0 * 40 + k8];
    bf16x8 a1 = *(bf16x8*)&lA[(rA0 + 16) * 40 + k8];
    bf16x8 b0 = *(bf16x8*)&lB[cB0 * 40 + k8];
    bf16x8 b1 = *(bf16x8*)&lB[(cB0 + 16) * 40 + k8];
    acc[0][0] = mfma16(a0, b0, acc[0][0]);
    acc[0][1] = mfma16(a0, b1, acc[0][1]);
    acc[1][0] = mfma16(a1, b0, acc[1][0]);
    acc[1][1] = mfma16(a1, b1, acc[1][1]);
    __syncthreads();
  }
#pragma unroll
  for (int mi = 0; mi < 2; ++mi)
#pragma unroll
    for (int ni = 0; ni < 2; ++ni)
#pragma unroll
      for (int r = 0; r < 4; ++r) {
        int row = m0 + wr * 32 + mi * 16 + ((lane >> 4) << 2) + r;
        int col = n0 + wc * 32 + ni * 16 + (lane & 15);
        float vv = acc[mi][ni][r];
        if (EP == 0) {
          ((short*)outp)[row * GD + col] = f2b(vv);
        } else if (EP == 1) {
          int b = row >> 10, l = row & 1023, h = col >> 6, dh = col & 63;
          ((short*)outp)[(((b << 4) + h) * 1024 + l) * 64 + dh] = f2b(vv);
        } else {
          ((float*)outp)[row * GD + col] = vv + resid[row * GD + col];
        }
      }
}

// ---------------------------------------------------------------- attention
// one block = one (b,h) x 32 query rows; vector flash with P-band staging.
#define QS 68
#define KS 72
#define VS 72
#define PS 72
#define SS 68
#define OS 68
__global__ __launch_bounds__(256) void attn_k(const short* __restrict__ q,
                                              const short* __restrict__ k,
                                              const short* __restrict__ v,
                                              const short* __restrict__ P,
                                              short* __restrict__ out) {
  const int bx = blockIdx.x;
  const int bh = bx >> 5;
  const int it = bx & 31;
  const int b = bh >> 4, h = bh & 15;
  const int i0 = it << 5;
  const short* qb = q + (size_t)bh * 1024 * 64;
  const short* kb = k + (size_t)bh * 1024 * 64;
  const short* vb = v + (size_t)bh * 1024 * 64;

  __shared__ __align__(16) float sQ[32 * QS];
  __shared__ __align__(16) short sK[64 * KS];
  __shared__ __align__(16) short sV[64 * VS];
  __shared__ __align__(16) short sP[96 * PS];
  __shared__ __align__(16) float sS[32 * SS];
  __shared__ __align__(16) float sO[32 * OS];
  __shared__ float sM[32], sL[32], sSc[32];

  const int t = threadIdx.x;
  {
    int a = t >> 3, c0 = (t & 7) << 3;
    s16x8 qv = *(const s16x8*)&qb[(i0 + a) * 64 + c0];
#pragma unroll
    for (int e = 0; e < 8; ++e) {
      sQ[a * QS + c0 + e] = b2f(qv[e]);
      sO[a * OS + c0 + e] = 0.f;
    }
    if (t < 32) { sM[t] = -1e30f; sL[t] = 0.f; }
  }
  __syncthreads();

  for (int j0 = 0; j0 < 1024; j0 += 64) {
    {  // stage K,V tiles
      int j = t >> 2, c0 = (t & 3) << 4;
      *(s16x8*)&sK[j * KS + c0] = *(const s16x8*)&kb[(j0 + j) * 64 + c0];
      *(s16x8*)&sK[j * KS + c0 + 8] = *(const s16x8*)&kb[(j0 + j) * 64 + c0 + 8];
      *(s16x8*)&sV[j * VS + c0] = *(const s16x8*)&vb[(j0 + j) * 64 + c0];
      *(s16x8*)&sV[j * VS + c0 + 8] = *(const s16x8*)&vb[(j0 + j) * 64 + c0 + 8];
    }
    {  // stage P band: offsets ob .. ob+95 (rows 0..94 read)
      int ob = 1023 + j0 - i0 - 31;
#pragma unroll
      for (int u = 0; u < 3; ++u) {
        int gi = t + (u << 8);
        int r = gi >> 3, c0 = (gi & 7) << 3;
        int o = ob + r;
        o = o < 0 ? 0 : (o > 2046 ? 2046 : o);
        *(s16x8*)&sP[r * PS + c0] = *(const s16x8*)&P[(size_t)o * 1024 + (h << 6) + c0];
      }
    }
    __syncthreads();
    {  // scores: s = (q.k + q.p[j-i+1023]) / 8
      int a = t >> 3, j1 = (t & 7) << 3;
      for (int jj = j1; jj < j1 + 8; ++jj) {
        const s16x8* kp = (const s16x8*)&sK[jj * KS];
        const s16x8* pp = (const s16x8*)&sP[(jj - a + 31) * PS];
        const float* qp = &sQ[a * QS];
        float ac = 0.f, bd = 0.f;
#pragma unroll
        for (int u = 0; u < 8; ++u) {
          s16x8 kv = kp[u], pv = pp[u];
#pragma unroll
          for (int e = 0; e < 8; ++e) {
            float qq = qp[u * 8 + e];
            ac += qq * b2f(kv[e]);
            bd += qq * b2f(pv[e]);
          }
        }
        sS[a * SS + jj] = (ac + bd) * 0.125f;
      }
    }
    __syncthreads();
    {  // online softmax update
      int a = t >> 3, sub = t & 7;
      float mx = -1e30f;
#pragma unroll
      for (int u = 0; u < 8; ++u) mx = fmaxf(mx, sS[a * SS + sub + (u << 3)]);
      mx = fmaxf(mx, __shfl_xor(mx, 1));
      mx = fmaxf(mx, __shfl_xor(mx, 2));
      mx = fmaxf(mx, __shfl_xor(mx, 4));
      float mo = sM[a];
      float nm = fmaxf(mo, mx);
      float sum = 0.f;
#pragma unroll
      for (int u = 0; u < 8; ++u) {
        int idx = a * SS + sub + (u << 3);
        float p = __expf(sS[idx] - nm);
        sS[idx] = p;
        sum += p;
      }
      sum += __shfl_xor(sum, 1);
      sum += __shfl_xor(sum, 2);
      sum += __shfl_xor(sum, 4);
      if (sub == 0) {
        float sc = __expf(mo - nm);
        sL[a] = sL[a] * sc + sum;
        sSc[a] = sc;
        sM[a] = nm;
      }
    }
    __syncthreads();
    {  // O = O*scale + P.V
      int a = t >> 3, d0 = (t & 7) << 3;
      float o[8];
      float sc = sSc[a];
#pragma unroll
      for (int e = 0; e < 8; ++e) o[e] = sO[a * OS + d0 + e] * sc;
      for (int jj = 0; jj < 64; ++jj) {
        float p = sS[a * SS + jj];
        s16x8 vv = *(const s16x8*)&sV[jj * VS + d0];
#pragma unroll
        for (int e = 0; e < 8; ++e) o[e] += p * b2f(vv[e]);
      }
#pragma unroll
      for (int e = 0; e < 8; ++e) sO[a * OS + d0 + e] = o[e];
    }
    __syncthreads();
  }
  {
    int a = t >> 3, d0 = (t & 7) << 3;
    float rl = 1.f / sL[a];
    int row = b * 1024 + i0 + a;
#pragma unroll
    for (int e = 0; e < 8; ++e)
      out[row * 1024 + (h << 6) + d0 + e] = f2b(sO[a * OS + d0 + e] * rl);
  }
}

// ---------------------------------------------------------------- MoE gate (full f32 path)
// recomputes LN2 in f32 so expert selection matches the f32 reference exactly
__global__ __launch_bounds__(256) void gate_k(const float* __restrict__ x,
                                              const float* __restrict__ g,
                                              const float* __restrict__ bb,
                                              const float* __restrict__ selw,
                                              float* __restrict__ topv,
                                              int* __restrict__ topi) {
  int tok = blockIdx.x;
  int t = threadIdx.x;
  __shared__ float sT[1024];
  __shared__ float red1[4], red2[4];
  __shared__ float sG[32];
  float v[4];
#pragma unroll
  for (int i = 0; i < 4; ++i) v[i] = x[tok * 1024 + t + (i << 8)];
  float s = v[0] + v[1] + v[2] + v[3];
#pragma unroll
  for (int m = 1; m < 64; m <<= 1) s += __shfl_xor(s, m);
  if ((t & 63) == 0) red1[t >> 6] = s;
  __syncthreads();
  float mean = (red1[0] + red1[1] + red1[2] + red1[3]) * (1.f / 1024.f);
  float d2 = 0.f;
#pragma unroll
  for (int i = 0; i < 4; ++i) { float d = v[i] - mean; d2 += d * d; }
#pragma unroll
  for (int m = 1; m < 64; m <<= 1) d2 += __shfl_xor(d2, m);
  if ((t & 63) == 0) red2[t >> 6] = d2;
  __syncthreads();
  float var = (red2[0] + red2[1] + red2[2] + red2[3]) * (1.f / 1024.f);
  float rstd = rsqrtf(var + 1e-5f);
#pragma unroll
  for (int i = 0; i < 4; ++i) {
    int c = t + (i << 8);
    sT[c] = (v[i] - mean) * rstd * g[c] + bb[c];
  }
  __syncthreads();
  if (t < 32) {
    float acc = 0.f;
    for (int d = 0; d < 1024; ++d) acc += sT[d] * selw[d * 32 + t];
    sG[t] = acc;
  }
  __syncthreads();
  if (t == 0) {
    bool used[32];
    for (int e = 0; e < 32; ++e) used[e] = false;
    for (int kk = 0; kk < 4; ++kk) {
      int bi = 0;
      float bvv = -1e30f;
      for (int e = 0; e < 32; ++e)
        if (!used[e] && sG[e] > bvv) { bvv = sG[e]; bi = e; }
      used[bi] = true;
      topi[tok * 4 + kk] = bi;
      topv[tok * 4 + kk] = 1.f / (1.f + __expf(-bvv));
    }
  }
}

// ---------------------------------------------------------------- MoE FFN (f32 out)
__global__ __launch_bounds__(256) void moe_k(const short* __restrict__ x2,
                                             const float* __restrict__ xres,
                                             const short* __restrict__ keys,
                                             const short* __restrict__ vals,
                                             const float* __restrict__ topv,
                                             const int* __restrict__ topi,
                                             float* __restrict__ out) {
  int tok = blockIdx.x;
  int t = threadIdx.x;
  __shared__ float sT[1024];
  __shared__ float sHp[2][128];
  __shared__ float sH[128];
#pragma unroll
  for (int i = 0; i < 4; ++i) sT[t + (i << 8)] = b2f(x2[tok * 1024 + t + (i << 8)]);
  float y[4] = {0.f, 0.f, 0.f, 0.f};
  __syncthreads();
  for (int kk = 0; kk < 4; ++kk) {
    int e = topi[tok * 4 + kk];
    float g = topv[tok * 4 + kk];
    int s = t & 127, half = t >> 7;
    const short* kp = keys + (size_t)e * 1024 * 128 + s;
    float acc = 0.f;
    int d0 = half << 9;
    for (int d = d0; d < d0 + 512; ++d) acc += sT[d] * b2f(kp[(size_t)d * 128]);
    sHp[half][s] = acc;
    __syncthreads();
    if (t < 128) sH[t] = fmaxf(sHp[0][t] + sHp[1][t], 0.f);
    __syncthreads();
    const short* vp = vals + (size_t)e * 128 * 1024;
#pragma unroll
    for (int u = 0; u < 4; ++u) {
      int d = t + (u << 8);
      float acc2 = 0.f;
      for (int s2 = 0; s2 < 128; ++s2) acc2 += sH[s2] * b2f(vp[s2 * 1024 + d]);
      y[u] += g * acc2;
    }
    __syncthreads();
  }
#pragma unroll
  for (int u = 0; u < 4; ++u) {
    int d = t + (u << 8);
    out[tok * 1024 + d] = xres[tok * 1024 + d] + y[u];
  }
}

// ---------------------------------------------------------------- launch
extern "C" void kernel_launch(void* const* d_in, const int* in_sizes, int n_in,
                              void* d_out, int out_size, void* d_ws, size_t ws_size,
                              hipStream_t stream) {
  const float* src = (const float*)d_in[0];
  const float* ln1g = (const float*)d_in[6];
  const float* ln1b = (const float*)d_in[7];
  const float* ln2g = (const float*)d_in[8];
  const float* ln2b = (const float*)d_in[9];
  const float* selw = (const float*)d_in[10];

  char* ws = (char*)d_ws;
  short* x2a = (short*)(ws + (size_t)0);           // 4MB bf16 LN1 out
  short* pos = (short*)(ws + ((size_t)4 << 20));   // 4MB
  short* P = (short*)(ws + ((size_t)8 << 20));     // 4MB
  short* q = (short*)(ws + ((size_t)12 << 20));    // 4MB [B,H,L,DH]
  short* k = (short*)(ws + ((size_t)16 << 20));    // 4MB
  short* v = (short*)(ws + ((size_t)20 << 20));    // 4MB
  short* ao = (short*)(ws + ((size_t)24 << 20));   // 4MB attn out token-major
  short* x2b = (short*)(ws + ((size_t)28 << 20));  // 4MB bf16 LN2 out
  float* x = (float*)(ws + ((size_t)32 << 20));    // 8MB f32 residual1
  float* topv = (float*)(ws + ((size_t)40 << 20));
  int* topi = (int*)(ws + ((size_t)40 << 20) + (32 << 10));
  short* cWq = (short*)(ws + ((size_t)41 << 20));  // 2MB each
  short* cWk = (short*)(ws + ((size_t)43 << 20));
  short* cWv = (short*)(ws + ((size_t)45 << 20));
  short* cWo = (short*)(ws + ((size_t)47 << 20));
  short* cWp = (short*)(ws + ((size_t)49 << 20));
  short* cKeys = (short*)(ws + ((size_t)51 << 20));  // 8MB
  short* cVals = (short*)(ws + ((size_t)59 << 20));  // 8MB

  conv_k<<<512, 256, 0, stream>>>((const float*)d_in[1], cWq, 1048576);
  conv_k<<<512, 256, 0, stream>>>((const float*)d_in[2], cWk, 1048576);
  conv_k<<<512, 256, 0, stream>>>((const float*)d_in[3], cWv, 1048576);
  conv_k<<<512, 256, 0, stream>>>((const float*)d_in[4], cWo, 1048576);
  conv_k<<<512, 256, 0, stream>>>((const float*)d_in[5], cWp, 1048576);
  conv_k<<<1024, 256, 0, stream>>>((const float*)d_in[11], cKeys, 4194304);
  conv_k<<<1024, 256, 0, stream>>>((const float*)d_in[12], cVals, 4194304);

  dim3 gg(16, 32);  // (N/64, M/64)
  pos_k<<<2048, 256, 0, stream>>>(pos);
  ln_k<<<2048, 256, 0, stream>>>(src, ln1g, ln1b, x2a);
  gemm_k<1><<<gg, 256, 0, stream>>>(x2a, cWq, q, nullptr);
  gemm_k<1><<<gg, 256, 0, stream>>>(x2a, cWk, k, nullptr);
  gemm_k<1><<<gg, 256, 0, stream>>>(x2a, cWv, v, nullptr);
  gemm_k<0><<<gg, 256, 0, stream>>>(pos, cWp, P, nullptr);
  attn_k<<<1024, 256, 0, stream>>>(q, k, v, P, ao);
  gemm_k<2><<<gg, 256, 0, stream>>>(ao, cWo, x, src);
  ln_k<<<2048, 256, 0, stream>>>(x, ln2g, ln2b, x2b);
  gate_k<<<2048, 256, 0, stream>>>(x, ln2g, ln2b, selw, topv, topi);
  moe_k<<<2048, 256, 0, stream>>>(x2b, x, cKeys, cVals, topv, topi, (float*)d_out);
}

// Round 6
// 685.766 us; speedup vs baseline: 1.4512x; 1.4512x over previous
//
#include <hip/hip_runtime.h>
#include <hip/hip_bf16.h>
#include <cmath>

typedef __attribute__((ext_vector_type(8))) short s16x8;
typedef __attribute__((ext_vector_type(8))) __bf16 bf16x8;
typedef __attribute__((ext_vector_type(4))) float f32x4;

__device__ __forceinline__ float b2f(short u) {
  union { unsigned int u32; float f; } c;
  c.u32 = ((unsigned int)(unsigned short)u) << 16;
  return c.f;
}
__device__ __forceinline__ short f2b(float f) {
  __hip_bfloat16 h = __float2bfloat16(f);
  return *reinterpret_cast<short*>(&h);
}

__device__ __forceinline__ f32x4 mfma16(bf16x8 a, bf16x8 b, f32x4 c) {
  return __builtin_amdgcn_mfma_f32_16x16x32_bf16(a, b, c, 0, 0, 0);
}

// ---------------------------------------------------------------- f32 -> bf16
__global__ __launch_bounds__(256) void conv_k(const float* __restrict__ in,
                                              short* __restrict__ out, int n) {
  int stride = gridDim.x << 8;
  for (int i = (blockIdx.x << 8) + threadIdx.x; i < n; i += stride)
    out[i] = f2b(in[i]);
}

// ---------------------------------------------------------------- pos table
// rows 0..2046: [sin(pos*inv_c) | cos(pos*inv_c)], pos = 1023 - row; row 2047 = 0
__global__ __launch_bounds__(256) void pos_k(short* __restrict__ out) {
  int row = blockIdx.x;
  int t = threadIdx.x;
#pragma unroll
  for (int i = 0; i < 4; ++i) {
    int c = t + (i << 8);
    float val = 0.f;
    if (row < 2047) {
      int f = (c < 512) ? c : c - 512;
      float inv = expf(-(float)f * (float)(9.210340371976184 / 512.0));
      float ang = (float)(1023 - row) * inv;
      val = (c < 512) ? sinf(ang) : cosf(ang);
    }
    out[row * 1024 + c] = f2b(val);
  }
}

// ---------------------------------------------------------------- layernorm (f32 in, bf16 out)
__global__ __launch_bounds__(256) void ln_k(const float* __restrict__ in,
                                            const float* __restrict__ g,
                                            const float* __restrict__ bb,
                                            short* __restrict__ out) {
  int row = blockIdx.x;
  int t = threadIdx.x;
  float v[4];
#pragma unroll
  for (int i = 0; i < 4; ++i) v[i] = in[row * 1024 + t + (i << 8)];
  __shared__ float red1[4], red2[4];
  float s = v[0] + v[1] + v[2] + v[3];
#pragma unroll
  for (int m = 1; m < 64; m <<= 1) s += __shfl_xor(s, m);
  if ((t & 63) == 0) red1[t >> 6] = s;
  __syncthreads();
  float mean = (red1[0] + red1[1] + red1[2] + red1[3]) * (1.f / 1024.f);
  float d2 = 0.f;
#pragma unroll
  for (int i = 0; i < 4; ++i) { float d = v[i] - mean; d2 += d * d; }
#pragma unroll
  for (int m = 1; m < 64; m <<= 1) d2 += __shfl_xor(d2, m);
  if ((t & 63) == 0) red2[t >> 6] = d2;
  __syncthreads();
  float var = (red2[0] + red2[1] + red2[2] + red2[3]) * (1.f / 1024.f);
  float rstd = rsqrtf(var + 1e-5f);
#pragma unroll
  for (int i = 0; i < 4; ++i) {
    int c = t + (i << 8);
    out[row * 1024 + c] = f2b((v[i] - mean) * rstd * g[c] + bb[c]);
  }
}

// ---------------------------------------------------------------- MFMA GEMM
// C[M=2048, N=1024] = A[2048,1024] @ B[1024,1024], A,B bf16 row-major.
// EP 0: bf16 row-major out; EP 1: qkv layout [B,H,L,DH]; EP 2: f32 out = acc + resid(f32)
#define GD 1024
template <int EP>
__global__ __launch_bounds__(256) void gemm_k(const short* __restrict__ A,
                                              const short* __restrict__ B,
                                              void* __restrict__ outp,
                                              const float* __restrict__ resid) {
  __shared__ __align__(16) short lA[64 * 40];
  __shared__ __align__(16) short lB[64 * 40];
  const int tid = threadIdx.x;
  const int wave = tid >> 6, lane = tid & 63;
  const int wr = wave >> 1, wc = wave & 1;
  const int m0 = blockIdx.y * 64, n0 = blockIdx.x * 64;
  f32x4 acc[2][2] = {};
  const int ar = tid >> 2, ak = (tid & 3) << 3;
  const int bk = tid >> 3, bn = (tid & 7) << 3;
  const int k8 = (lane >> 4) << 3;
  const int rA0 = wr * 32 + (lane & 15);
  const int cB0 = wc * 32 + (lane & 15);
  for (int kt = 0; kt < GD; kt += 32) {
    *(bf16x8*)&lA[ar * 40 + ak] = *(const bf16x8*)&A[(m0 + ar) * GD + kt + ak];
    s16x8 bv = *(const s16x8*)&B[(kt + bk) * GD + n0 + bn];
#pragma unroll
    for (int i = 0; i < 8; ++i) lB[(bn + i) * 40 + bk] = bv[i];
    __syncthreads();
    bf16x8 a0 = *(bf16x8*)&lA[rA0 * 40 + k8];
    bf16x8 a1 = *(bf16x8*)&lA[(rA0 + 16) * 40 + k8];
    bf16x8 b0 = *(bf16x8*)&lB[cB0 * 40 + k8];
    bf16x8 b1 = *(bf16x8*)&lB[(cB0 + 16) * 40 + k8];
    acc[0][0] = mfma16(a0, b0, acc[0][0]);
    acc[0][1] = mfma16(a0, b1, acc[0][1]);
    acc[1][0] = mfma16(a1, b0, acc[1][0]);
    acc[1][1] = mfma16(a1, b1, acc[1][1]);
    __syncthreads();
  }
#pragma unroll
  for (int mi = 0; mi < 2; ++mi)
#pragma unroll
    for (int ni = 0; ni < 2; ++ni)
#pragma unroll
      for (int r = 0; r < 4; ++r) {
        int row = m0 + wr * 32 + mi * 16 + ((lane >> 4) << 2) + r;
        int col = n0 + wc * 32 + ni * 16 + (lane & 15);
        float vv = acc[mi][ni][r];
        if (EP == 0) {
          ((short*)outp)[row * GD + col] = f2b(vv);
        } else if (EP == 1) {
          int b = row >> 10, l = row & 1023, h = col >> 6, dh = col & 63;
          ((short*)outp)[(((b << 4) + h) * 1024 + l) * 64 + dh] = f2b(vv);
        } else {
          ((float*)outp)[row * GD + col] = vv + resid[row * GD + col];
        }
      }
}

// ---------------------------------------------------------------- MFMA attention
// block = (b,h) x 64 q-rows (512 blocks, 2/CU); wave = 16 q-rows.
// Per 64-wide K-tile: AC = Q@K^T (MFMA), BD = Q@Pband^T -> 16x80 band tile T (MFMA),
// band gather bd[a,jj]=T[a,15+jj-a] via per-wave LDS, online softmax in registers,
// PV = P@V (MFMA, P re-staged bf16 via LDS for A-frag layout).
#define KP 72
#define VP 72
#define PBP 72
#define TP 84
#define SPP 72
__global__ __launch_bounds__(256) void attn_k(const short* __restrict__ q,
                                              const short* __restrict__ k,
                                              const short* __restrict__ v,
                                              const short* __restrict__ P,
                                              short* __restrict__ out) {
  __shared__ __align__(16) short sK[64 * KP];
  __shared__ __align__(16) short sVT[64 * VP];
  __shared__ __align__(16) short sPB[128 * PBP];
  __shared__ __align__(16) float sT[4 * 16 * TP];
  __shared__ __align__(16) short sP[4 * 16 * SPP];

  const int bx = blockIdx.x;
  const int bh = bx >> 4;     // 0..31
  const int chunk = bx & 15;  // 0..15
  const int b = bh >> 4, h = bh & 15;
  const int i0 = chunk << 6;
  const int t = threadIdx.x;
  const int w = t >> 6;
  const int lane = t & 63;
  const int cl = lane & 15;  // output-col / A-frag row
  const int g = lane >> 4;   // k-group
  const size_t base = (size_t)bh << 16;
  const short* qb = q + base;
  const short* kb = k + base;
  const short* vb = v + base;

  // Q fragments: row = i0 + w*16 + cl, k = kk*32 + g*8 + e
  bf16x8 qf[2];
  {
    const short* qr = qb + (i0 + w * 16 + cl) * 64 + g * 8;
    qf[0] = *(const bf16x8*)&qr[0];
    qf[1] = *(const bf16x8*)&qr[32];
  }

  f32x4 acc_o[4] = {};  // O[16 rows][64 dh], col-tile nd
  float m_reg[4], l_reg[4];
#pragma unroll
  for (int r = 0; r < 4; ++r) { m_reg[r] = -1e30f; l_reg[r] = 0.f; }

  float* sTw = sT + w * (16 * TP);
  short* sPw = sP + w * (16 * SPP);
  const int a_row = g * 4;          // + r = wave-local q row
  const int prow0 = 48 - w * 16 + cl;  // band B-frag base row in sPB

  for (int j0 = 0; j0 < 1024; j0 += 64) {
    __syncthreads();
    {  // stage K rows + V transposed
      int c0 = t << 1;
#pragma unroll
      for (int u = 0; u < 2; ++u) {
        int c = c0 + u;
        int row = c >> 3, col8 = (c & 7) << 3;
        *(s16x8*)&sK[row * KP + col8] = *(const s16x8*)&kb[(j0 + row) * 64 + col8];
        s16x8 vv = *(const s16x8*)&vb[(j0 + row) * 64 + col8];
#pragma unroll
        for (int e = 0; e < 8; ++e) sVT[(col8 + e) * VP + row] = vv[e];
      }
      // stage P band: 128 rows, offsets ob..ob+127 (always within [0,2047])
      int ob = 960 - i0 + j0;
#pragma unroll
      for (int u = 0; u < 4; ++u) {
        int c = t + (u << 8);
        int row = c >> 3, col8 = (c & 7) << 3;
        *(s16x8*)&sPB[row * PBP + col8] =
            *(const s16x8*)&P[(size_t)(ob + row) * 1024 + (h << 6) + col8];
      }
    }
    __syncthreads();

    // ---- AC = Q@K^T, band T = Q@Pband^T
    f32x4 acc_s[4] = {};
    f32x4 acc_t[5] = {};
#pragma unroll
    for (int kk = 0; kk < 2; ++kk) {
      bf16x8 a = qf[kk];
      int koff = kk * 32 + g * 8;
#pragma unroll
      for (int nj = 0; nj < 4; ++nj) {
        bf16x8 bfr = *(const bf16x8*)&sK[(nj * 16 + cl) * KP + koff];
        acc_s[nj] = mfma16(a, bfr, acc_s[nj]);
      }
#pragma unroll
      for (int nt = 0; nt < 5; ++nt) {
        bf16x8 bfr = *(const bf16x8*)&sPB[(prow0 + nt * 16) * PBP + koff];
        acc_t[nt] = mfma16(a, bfr, acc_t[nt]);
      }
    }
    // write band tile T (per-wave region; in-wave DS ops are in-order)
#pragma unroll
    for (int nt = 0; nt < 5; ++nt)
#pragma unroll
      for (int r = 0; r < 4; ++r)
        sTw[(a_row + r) * TP + nt * 16 + cl] = acc_t[nt][r];

    // ---- gather band + online softmax
    float sval[4][4];
#pragma unroll
    for (int r = 0; r < 4; ++r) {
      int a = a_row + r;
      int abase = a * (TP - 1) + 15 + cl;  // a*TP + (15 + cl - a)
      float mr = -1e30f;
#pragma unroll
      for (int ni = 0; ni < 4; ++ni) {
        float sv = (acc_s[ni][r] + sTw[abase + ni * 16]) * 0.125f;
        sval[r][ni] = sv;
        mr = fmaxf(mr, sv);
      }
      mr = fmaxf(mr, __shfl_xor(mr, 1));
      mr = fmaxf(mr, __shfl_xor(mr, 2));
      mr = fmaxf(mr, __shfl_xor(mr, 4));
      mr = fmaxf(mr, __shfl_xor(mr, 8));
      float nm = fmaxf(m_reg[r], mr);
      float sc = __expf(m_reg[r] - nm);
      m_reg[r] = nm;
      float ls = 0.f;
#pragma unroll
      for (int ni = 0; ni < 4; ++ni) {
        float p = __expf(sval[r][ni] - nm);
        sval[r][ni] = p;
        ls += p;
      }
      ls += __shfl_xor(ls, 1);
      ls += __shfl_xor(ls, 2);
      ls += __shfl_xor(ls, 4);
      ls += __shfl_xor(ls, 8);
      l_reg[r] = l_reg[r] * sc + ls;
#pragma unroll
      for (int nd = 0; nd < 4; ++nd) acc_o[nd][r] *= sc;
#pragma unroll
      for (int ni = 0; ni < 4; ++ni)
        sPw[a * SPP + ni * 16 + cl] = f2b(sval[r][ni]);
    }

    // ---- PV: O += P @ V
#pragma unroll
    for (int kk = 0; kk < 2; ++kk) {
      int koff = kk * 32 + g * 8;
      bf16x8 a = *(const bf16x8*)&sPw[cl * SPP + koff];
#pragma unroll
      for (int nd = 0; nd < 4; ++nd) {
        bf16x8 bfr = *(const bf16x8*)&sVT[(nd * 16 + cl) * VP + koff];
        acc_o[nd] = mfma16(a, bfr, acc_o[nd]);
      }
    }
  }
  // epilogue: O / l -> out (token-major bf16)
  {
    int orow = b * 1024 + i0 + w * 16 + a_row;
#pragma unroll
    for (int r = 0; r < 4; ++r) {
      float rl = 1.f / l_reg[r];
      int row = orow + r;
#pragma unroll
      for (int nd = 0; nd < 4; ++nd)
        out[row * 1024 + (h << 6) + nd * 16 + cl] = f2b(acc_o[nd][r] * rl);
    }
  }
}

// ---------------------------------------------------------------- MoE gate (full f32 path)
__global__ __launch_bounds__(256) void gate_k(const float* __restrict__ x,
                                              const float* __restrict__ g,
                                              const float* __restrict__ bb,
                                              const float* __restrict__ selw,
                                              float* __restrict__ topv,
                                              int* __restrict__ topi) {
  int tok = blockIdx.x;
  int t = threadIdx.x;
  __shared__ float sT[1024];
  __shared__ float red1[4], red2[4];
  __shared__ float sG[32];
  float v[4];
#pragma unroll
  for (int i = 0; i < 4; ++i) v[i] = x[tok * 1024 + t + (i << 8)];
  float s = v[0] + v[1] + v[2] + v[3];
#pragma unroll
  for (int m = 1; m < 64; m <<= 1) s += __shfl_xor(s, m);
  if ((t & 63) == 0) red1[t >> 6] = s;
  __syncthreads();
  float mean = (red1[0] + red1[1] + red1[2] + red1[3]) * (1.f / 1024.f);
  float d2 = 0.f;
#pragma unroll
  for (int i = 0; i < 4; ++i) { float d = v[i] - mean; d2 += d * d; }
#pragma unroll
  for (int m = 1; m < 64; m <<= 1) d2 += __shfl_xor(d2, m);
  if ((t & 63) == 0) red2[t >> 6] = d2;
  __syncthreads();
  float var = (red2[0] + red2[1] + red2[2] + red2[3]) * (1.f / 1024.f);
  float rstd = rsqrtf(var + 1e-5f);
#pragma unroll
  for (int i = 0; i < 4; ++i) {
    int c = t + (i << 8);
    sT[c] = (v[i] - mean) * rstd * g[c] + bb[c];
  }
  __syncthreads();
  if (t < 32) {
    float acc = 0.f;
    for (int d = 0; d < 1024; ++d) acc += sT[d] * selw[d * 32 + t];
    sG[t] = acc;
  }
  __syncthreads();
  if (t == 0) {
    bool used[32];
    for (int e = 0; e < 32; ++e) used[e] = false;
    for (int kk = 0; kk < 4; ++kk) {
      int bi = 0;
      float bvv = -1e30f;
      for (int e = 0; e < 32; ++e)
        if (!used[e] && sG[e] > bvv) { bvv = sG[e]; bi = e; }
      used[bi] = true;
      topi[tok * 4 + kk] = bi;
      topv[tok * 4 + kk] = 1.f / (1.f + __expf(-bvv));
    }
  }
}

// ---------------------------------------------------------------- MoE FFN (f32 out)
__global__ __launch_bounds__(256) void moe_k(const short* __restrict__ x2,
                                             const float* __restrict__ xres,
                                             const short* __restrict__ keys,
                                             const short* __restrict__ vals,
                                             const float* __restrict__ topv,
                                             const int* __restrict__ topi,
                                             float* __restrict__ out) {
  int tok = blockIdx.x;
  int t = threadIdx.x;
  __shared__ float sT[1024];
  __shared__ float sHp[2][128];
  __shared__ float sH[128];
#pragma unroll
  for (int i = 0; i < 4; ++i) sT[t + (i << 8)] = b2f(x2[tok * 1024 + t + (i << 8)]);
  float y[4] = {0.f, 0.f, 0.f, 0.f};
  __syncthreads();
  for (int kk = 0; kk < 4; ++kk) {
    int e = topi[tok * 4 + kk];
    float g = topv[tok * 4 + kk];
    int s = t & 127, half = t >> 7;
    const short* kp = keys + (size_t)e * 1024 * 128 + s;
    float acc = 0.f;
    int d0 = half << 9;
    for (int d = d0; d < d0 + 512; ++d) acc += sT[d] * b2f(kp[(size_t)d * 128]);
    sHp[half][s] = acc;
    __syncthreads();
    if (t < 128) sH[t] = fmaxf(sHp[0][t] + sHp[1][t], 0.f);
    __syncthreads();
    const short* vp = vals + (size_t)e * 128 * 1024;
#pragma unroll
    for (int u = 0; u < 4; ++u) {
      int d = t + (u << 8);
      float acc2 = 0.f;
      for (int s2 = 0; s2 < 128; ++s2) acc2 += sH[s2] * b2f(vp[s2 * 1024 + d]);
      y[u] += g * acc2;
    }
    __syncthreads();
  }
#pragma unroll
  for (int u = 0; u < 4; ++u) {
    int d = t + (u << 8);
    out[tok * 1024 + d] = xres[tok * 1024 + d] + y[u];
  }
}

// ---------------------------------------------------------------- launch
extern "C" void kernel_launch(void* const* d_in, const int* in_sizes, int n_in,
                              void* d_out, int out_size, void* d_ws, size_t ws_size,
                              hipStream_t stream) {
  const float* src = (const float*)d_in[0];
  const float* ln1g = (const float*)d_in[6];
  const float* ln1b = (const float*)d_in[7];
  const float* ln2g = (const float*)d_in[8];
  const float* ln2b = (const float*)d_in[9];
  const float* selw = (const float*)d_in[10];

  char* ws = (char*)d_ws;
  short* x2a = (short*)(ws + (size_t)0);           // 4MB bf16 LN1 out
  short* pos = (short*)(ws + ((size_t)4 << 20));   // 4MB
  short* P = (short*)(ws + ((size_t)8 << 20));     // 4MB
  short* q = (short*)(ws + ((size_t)12 << 20));    // 4MB [B,H,L,DH]
  short* k = (short*)(ws + ((size_t)16 << 20));    // 4MB
  short* v = (short*)(ws + ((size_t)20 << 20));    // 4MB
  short* ao = (short*)(ws + ((size_t)24 << 20));   // 4MB attn out token-major
  short* x2b = (short*)(ws + ((size_t)28 << 20));  // 4MB bf16 LN2 out
  float* x = (float*)(ws + ((size_t)32 << 20));    // 8MB f32 residual1
  float* topv = (float*)(ws + ((size_t)40 << 20));
  int* topi = (int*)(ws + ((size_t)40 << 20) + (32 << 10));
  short* cWq = (short*)(ws + ((size_t)41 << 20));  // 2MB each
  short* cWk = (short*)(ws + ((size_t)43 << 20));
  short* cWv = (short*)(ws + ((size_t)45 << 20));
  short* cWo = (short*)(ws + ((size_t)47 << 20));
  short* cWp = (short*)(ws + ((size_t)49 << 20));
  short* cKeys = (short*)(ws + ((size_t)51 << 20));  // 8MB
  short* cVals = (short*)(ws + ((size_t)59 << 20));  // 8MB

  conv_k<<<512, 256, 0, stream>>>((const float*)d_in[1], cWq, 1048576);
  conv_k<<<512, 256, 0, stream>>>((const float*)d_in[2], cWk, 1048576);
  conv_k<<<512, 256, 0, stream>>>((const float*)d_in[3], cWv, 1048576);
  conv_k<<<512, 256, 0, stream>>>((const float*)d_in[4], cWo, 1048576);
  conv_k<<<512, 256, 0, stream>>>((const float*)d_in[5], cWp, 1048576);
  conv_k<<<1024, 256, 0, stream>>>((const float*)d_in[11], cKeys, 4194304);
  conv_k<<<1024, 256, 0, stream>>>((const float*)d_in[12], cVals, 4194304);

  dim3 gg(16, 32);  // (N/64, M/64)
  pos_k<<<2048, 256, 0, stream>>>(pos);
  ln_k<<<2048, 256, 0, stream>>>(src, ln1g, ln1b, x2a);
  gemm_k<1><<<gg, 256, 0, stream>>>(x2a, cWq, q, nullptr);
  gemm_k<1><<<gg, 256, 0, stream>>>(x2a, cWk, k, nullptr);
  gemm_k<1><<<gg, 256, 0, stream>>>(x2a, cWv, v, nullptr);
  gemm_k<0><<<gg, 256, 0, stream>>>(pos, cWp, P, nullptr);
  attn_k<<<512, 256, 0, stream>>>(q, k, v, P, ao);
  gemm_k<2><<<gg, 256, 0, stream>>>(ao, cWo, x, src);
  ln_k<<<2048, 256, 0, stream>>>(x, ln2g, ln2b, x2b);
  gate_k<<<2048, 256, 0, stream>>>(x, ln2g, ln2b, selw, topv, topi);
  moe_k<<<2048, 256, 0, stream>>>(x2b, x, cKeys, cVals, topv, topi, (float*)d_out);
}

// Round 7
// 566.679 us; speedup vs baseline: 1.7562x; 1.2102x over previous
//
#include <hip/hip_runtime.h>
#include <hip/hip_bf16.h>
#include <cmath>

typedef __attribute__((ext_vector_type(8))) short s16x8;
typedef __attribute__((ext_vector_type(8))) __bf16 bf16x8;
typedef __attribute__((ext_vector_type(4))) float f32x4;

__device__ __forceinline__ float b2f(short u) {
  union { unsigned int u32; float f; } c;
  c.u32 = ((unsigned int)(unsigned short)u) << 16;
  return c.f;
}
__device__ __forceinline__ short f2b(float f) {
  __hip_bfloat16 h = __float2bfloat16(f);
  return *reinterpret_cast<short*>(&h);
}

__device__ __forceinline__ f32x4 mfma16(bf16x8 a, bf16x8 b, f32x4 c) {
  return __builtin_amdgcn_mfma_f32_16x16x32_bf16(a, b, c, 0, 0, 0);
}

// ---------------------------------------------------------------- f32 -> bf16
__global__ __launch_bounds__(256) void conv_k(const float* __restrict__ in,
                                              short* __restrict__ out, int n) {
  int stride = gridDim.x << 8;
  for (int i = (blockIdx.x << 8) + threadIdx.x; i < n; i += stride)
    out[i] = f2b(in[i]);
}

// ---------------------------------------------------------------- pos table
__global__ __launch_bounds__(256) void pos_k(short* __restrict__ out) {
  int row = blockIdx.x;
  int t = threadIdx.x;
#pragma unroll
  for (int i = 0; i < 4; ++i) {
    int c = t + (i << 8);
    float val = 0.f;
    if (row < 2047) {
      int f = (c < 512) ? c : c - 512;
      float inv = expf(-(float)f * (float)(9.210340371976184 / 512.0));
      float ang = (float)(1023 - row) * inv;
      val = (c < 512) ? sinf(ang) : cosf(ang);
    }
    out[row * 1024 + c] = f2b(val);
  }
}

// ---------------------------------------------------------------- layernorm (f32 in, bf16 out)
__global__ __launch_bounds__(256) void ln_k(const float* __restrict__ in,
                                            const float* __restrict__ g,
                                            const float* __restrict__ bb,
                                            short* __restrict__ out) {
  int row = blockIdx.x;
  int t = threadIdx.x;
  float v[4];
#pragma unroll
  for (int i = 0; i < 4; ++i) v[i] = in[row * 1024 + t + (i << 8)];
  __shared__ float red1[4], red2[4];
  float s = v[0] + v[1] + v[2] + v[3];
#pragma unroll
  for (int m = 1; m < 64; m <<= 1) s += __shfl_xor(s, m);
  if ((t & 63) == 0) red1[t >> 6] = s;
  __syncthreads();
  float mean = (red1[0] + red1[1] + red1[2] + red1[3]) * (1.f / 1024.f);
  float d2 = 0.f;
#pragma unroll
  for (int i = 0; i < 4; ++i) { float d = v[i] - mean; d2 += d * d; }
#pragma unroll
  for (int m = 1; m < 64; m <<= 1) d2 += __shfl_xor(d2, m);
  if ((t & 63) == 0) red2[t >> 6] = d2;
  __syncthreads();
  float var = (red2[0] + red2[1] + red2[2] + red2[3]) * (1.f / 1024.f);
  float rstd = rsqrtf(var + 1e-5f);
#pragma unroll
  for (int i = 0; i < 4; ++i) {
    int c = t + (i << 8);
    out[row * 1024 + c] = f2b((v[i] - mean) * rstd * g[c] + bb[c]);
  }
}

// ---------------------------------------------------------------- MFMA GEMM
#define GD 1024
template <int EP>
__global__ __launch_bounds__(256) void gemm_k(const short* __restrict__ A,
                                              const short* __restrict__ B,
                                              void* __restrict__ outp,
                                              const float* __restrict__ resid) {
  __shared__ __align__(16) short lA[64 * 40];
  __shared__ __align__(16) short lB[64 * 40];
  const int tid = threadIdx.x;
  const int wave = tid >> 6, lane = tid & 63;
  const int wr = wave >> 1, wc = wave & 1;
  const int m0 = blockIdx.y * 64, n0 = blockIdx.x * 64;
  f32x4 acc[2][2] = {};
  const int ar = tid >> 2, ak = (tid & 3) << 3;
  const int bk = tid >> 3, bn = (tid & 7) << 3;
  const int k8 = (lane >> 4) << 3;
  const int rA0 = wr * 32 + (lane & 15);
  const int cB0 = wc * 32 + (lane & 15);
  for (int kt = 0; kt < GD; kt += 32) {
    *(bf16x8*)&lA[ar * 40 + ak] = *(const bf16x8*)&A[(m0 + ar) * GD + kt + ak];
    s16x8 bv = *(const s16x8*)&B[(kt + bk) * GD + n0 + bn];
#pragma unroll
    for (int i = 0; i < 8; ++i) lB[(bn + i) * 40 + bk] = bv[i];
    __syncthreads();
    bf16x8 a0 = *(bf16x8*)&lA[rA0 * 40 + k8];
    bf16x8 a1 = *(bf16x8*)&lA[(rA0 + 16) * 40 + k8];
    bf16x8 b0 = *(bf16x8*)&lB[cB0 * 40 + k8];
    bf16x8 b1 = *(bf16x8*)&lB[(cB0 + 16) * 40 + k8];
    acc[0][0] = mfma16(a0, b0, acc[0][0]);
    acc[0][1] = mfma16(a0, b1, acc[0][1]);
    acc[1][0] = mfma16(a1, b0, acc[1][0]);
    acc[1][1] = mfma16(a1, b1, acc[1][1]);
    __syncthreads();
  }
#pragma unroll
  for (int mi = 0; mi < 2; ++mi)
#pragma unroll
    for (int ni = 0; ni < 2; ++ni)
#pragma unroll
      for (int r = 0; r < 4; ++r) {
        int row = m0 + wr * 32 + mi * 16 + ((lane >> 4) << 2) + r;
        int col = n0 + wc * 32 + ni * 16 + (lane & 15);
        float vv = acc[mi][ni][r];
        if (EP == 0) {
          ((short*)outp)[row * GD + col] = f2b(vv);
        } else if (EP == 1) {
          int b = row >> 10, l = row & 1023, h = col >> 6, dh = col & 63;
          ((short*)outp)[(((b << 4) + h) * 1024 + l) * 64 + dh] = f2b(vv);
        } else {
          ((float*)outp)[row * GD + col] = vv + resid[row * GD + col];
        }
      }
}

// ---------------------------------------------------------------- MFMA attention
#define KP 72
#define VP 72
#define PBP 72
#define TP 84
#define SPP 72
__global__ __launch_bounds__(256) void attn_k(const short* __restrict__ q,
                                              const short* __restrict__ k,
                                              const short* __restrict__ v,
                                              const short* __restrict__ P,
                                              short* __restrict__ out) {
  __shared__ __align__(16) short sK[64 * KP];
  __shared__ __align__(16) short sVT[64 * VP];
  __shared__ __align__(16) short sPB[128 * PBP];
  __shared__ __align__(16) float sT[4 * 16 * TP];
  __shared__ __align__(16) short sP[4 * 16 * SPP];

  const int bx = blockIdx.x;
  const int bh = bx >> 4;
  const int chunk = bx & 15;
  const int b = bh >> 4, h = bh & 15;
  const int i0 = chunk << 6;
  const int t = threadIdx.x;
  const int w = t >> 6;
  const int lane = t & 63;
  const int cl = lane & 15;
  const int g = lane >> 4;
  const size_t base = (size_t)bh << 16;
  const short* qb = q + base;
  const short* kb = k + base;
  const short* vb = v + base;

  bf16x8 qf[2];
  {
    const short* qr = qb + (i0 + w * 16 + cl) * 64 + g * 8;
    qf[0] = *(const bf16x8*)&qr[0];
    qf[1] = *(const bf16x8*)&qr[32];
  }

  f32x4 acc_o[4] = {};
  float m_reg[4], l_reg[4];
#pragma unroll
  for (int r = 0; r < 4; ++r) { m_reg[r] = -1e30f; l_reg[r] = 0.f; }

  float* sTw = sT + w * (16 * TP);
  short* sPw = sP + w * (16 * SPP);
  const int a_row = g * 4;
  const int prow0 = 48 - w * 16 + cl;

  for (int j0 = 0; j0 < 1024; j0 += 64) {
    __syncthreads();
    {
      int c0 = t << 1;
#pragma unroll
      for (int u = 0; u < 2; ++u) {
        int c = c0 + u;
        int row = c >> 3, col8 = (c & 7) << 3;
        *(s16x8*)&sK[row * KP + col8] = *(const s16x8*)&kb[(j0 + row) * 64 + col8];
        s16x8 vv = *(const s16x8*)&vb[(j0 + row) * 64 + col8];
#pragma unroll
        for (int e = 0; e < 8; ++e) sVT[(col8 + e) * VP + row] = vv[e];
      }
      int ob = 960 - i0 + j0;
#pragma unroll
      for (int u = 0; u < 4; ++u) {
        int c = t + (u << 8);
        int row = c >> 3, col8 = (c & 7) << 3;
        *(s16x8*)&sPB[row * PBP + col8] =
            *(const s16x8*)&P[(size_t)(ob + row) * 1024 + (h << 6) + col8];
      }
    }
    __syncthreads();

    f32x4 acc_s[4] = {};
    f32x4 acc_t[5] = {};
#pragma unroll
    for (int kk = 0; kk < 2; ++kk) {
      bf16x8 a = qf[kk];
      int koff = kk * 32 + g * 8;
#pragma unroll
      for (int nj = 0; nj < 4; ++nj) {
        bf16x8 bfr = *(const bf16x8*)&sK[(nj * 16 + cl) * KP + koff];
        acc_s[nj] = mfma16(a, bfr, acc_s[nj]);
      }
#pragma unroll
      for (int nt = 0; nt < 5; ++nt) {
        bf16x8 bfr = *(const bf16x8*)&sPB[(prow0 + nt * 16) * PBP + koff];
        acc_t[nt] = mfma16(a, bfr, acc_t[nt]);
      }
    }
#pragma unroll
    for (int nt = 0; nt < 5; ++nt)
#pragma unroll
      for (int r = 0; r < 4; ++r)
        sTw[(a_row + r) * TP + nt * 16 + cl] = acc_t[nt][r];

    float sval[4][4];
#pragma unroll
    for (int r = 0; r < 4; ++r) {
      int a = a_row + r;
      int abase = a * (TP - 1) + 15 + cl;
      float mr = -1e30f;
#pragma unroll
      for (int ni = 0; ni < 4; ++ni) {
        float sv = (acc_s[ni][r] + sTw[abase + ni * 16]) * 0.125f;
        sval[r][ni] = sv;
        mr = fmaxf(mr, sv);
      }
      mr = fmaxf(mr, __shfl_xor(mr, 1));
      mr = fmaxf(mr, __shfl_xor(mr, 2));
      mr = fmaxf(mr, __shfl_xor(mr, 4));
      mr = fmaxf(mr, __shfl_xor(mr, 8));
      float nm = fmaxf(m_reg[r], mr);
      float sc = __expf(m_reg[r] - nm);
      m_reg[r] = nm;
      float ls = 0.f;
#pragma unroll
      for (int ni = 0; ni < 4; ++ni) {
        float p = __expf(sval[r][ni] - nm);
        sval[r][ni] = p;
        ls += p;
      }
      ls += __shfl_xor(ls, 1);
      ls += __shfl_xor(ls, 2);
      ls += __shfl_xor(ls, 4);
      ls += __shfl_xor(ls, 8);
      l_reg[r] = l_reg[r] * sc + ls;
#pragma unroll
      for (int nd = 0; nd < 4; ++nd) acc_o[nd][r] *= sc;
#pragma unroll
      for (int ni = 0; ni < 4; ++ni)
        sPw[a * SPP + ni * 16 + cl] = f2b(sval[r][ni]);
    }

#pragma unroll
    for (int kk = 0; kk < 2; ++kk) {
      int koff = kk * 32 + g * 8;
      bf16x8 a = *(const bf16x8*)&sPw[cl * SPP + koff];
#pragma unroll
      for (int nd = 0; nd < 4; ++nd) {
        bf16x8 bfr = *(const bf16x8*)&sVT[(nd * 16 + cl) * VP + koff];
        acc_o[nd] = mfma16(a, bfr, acc_o[nd]);
      }
    }
  }
  {
    int orow = b * 1024 + i0 + w * 16 + a_row;
#pragma unroll
    for (int r = 0; r < 4; ++r) {
      float rl = 1.f / l_reg[r];
      int row = orow + r;
#pragma unroll
      for (int nd = 0; nd < 4; ++nd)
        out[row * 1024 + (h << 6) + nd * 16 + cl] = f2b(acc_o[nd][r] * rl);
    }
  }
}

// ---------------------------------------------------------------- MoE gate (full f32 path)
__global__ __launch_bounds__(256) void gate_k(const float* __restrict__ x,
                                              const float* __restrict__ g,
                                              const float* __restrict__ bb,
                                              const float* __restrict__ selw,
                                              float* __restrict__ topv,
                                              int* __restrict__ topi) {
  int tok = blockIdx.x;
  int t = threadIdx.x;
  __shared__ float sT[1024];
  __shared__ float red1[4], red2[4];
  __shared__ float sG[32];
  float v[4];
#pragma unroll
  for (int i = 0; i < 4; ++i) v[i] = x[tok * 1024 + t + (i << 8)];
  float s = v[0] + v[1] + v[2] + v[3];
#pragma unroll
  for (int m = 1; m < 64; m <<= 1) s += __shfl_xor(s, m);
  if ((t & 63) == 0) red1[t >> 6] = s;
  __syncthreads();
  float mean = (red1[0] + red1[1] + red1[2] + red1[3]) * (1.f / 1024.f);
  float d2 = 0.f;
#pragma unroll
  for (int i = 0; i < 4; ++i) { float d = v[i] - mean; d2 += d * d; }
#pragma unroll
  for (int m = 1; m < 64; m <<= 1) d2 += __shfl_xor(d2, m);
  if ((t & 63) == 0) red2[t >> 6] = d2;
  __syncthreads();
  float var = (red2[0] + red2[1] + red2[2] + red2[3]) * (1.f / 1024.f);
  float rstd = rsqrtf(var + 1e-5f);
#pragma unroll
  for (int i = 0; i < 4; ++i) {
    int c = t + (i << 8);
    sT[c] = (v[i] - mean) * rstd * g[c] + bb[c];
  }
  __syncthreads();
  if (t < 32) {
    float acc = 0.f;
    for (int d = 0; d < 1024; ++d) acc += sT[d] * selw[d * 32 + t];
    sG[t] = acc;
  }
  __syncthreads();
  if (t == 0) {
    bool used[32];
    for (int e = 0; e < 32; ++e) used[e] = false;
    for (int kk = 0; kk < 4; ++kk) {
      int bi = 0;
      float bvv = -1e30f;
      for (int e = 0; e < 32; ++e)
        if (!used[e] && sG[e] > bvv) { bvv = sG[e]; bi = e; }
      used[bi] = true;
      topi[tok * 4 + kk] = bi;
      topv[tok * 4 + kk] = 1.f / (1.f + __expf(-bvv));
    }
  }
}

// ---------------------------------------------------------------- MoE bucketing
#define CAP 2048
__global__ __launch_bounds__(32) void zero_k(int* __restrict__ cnt) {
  cnt[threadIdx.x] = 0;
}
__global__ __launch_bounds__(256) void bucket_k(const int* __restrict__ topi,
                                                const float* __restrict__ topv,
                                                int* __restrict__ cnt,
                                                int* __restrict__ toklist,
                                                float* __restrict__ gatelist) {
  int tok = (blockIdx.x << 8) + threadIdx.x;
#pragma unroll
  for (int kk = 0; kk < 4; ++kk) {
    int e = topi[tok * 4 + kk];
    float gv = topv[tok * 4 + kk];
    int pos = atomicAdd(&cnt[e], 1);
    toklist[e * CAP + pos] = tok;
    gatelist[e * CAP + pos] = gv;
  }
}

// ---------------------------------------------------------------- residual copy (out = xres)
__global__ __launch_bounds__(256) void cp_k(const float* __restrict__ in,
                                            float* __restrict__ out) {
  int i = (blockIdx.x << 8) + threadIdx.x;
  *(f32x4*)&out[i << 2] = *(const f32x4*)&in[i << 2];
}

// ---------------------------------------------------------------- MoE up: h = relu(X[toks] @ keys[e])
// M=64 tokens, N=128, K=1024
__global__ __launch_bounds__(256) void moe_up_k(const short* __restrict__ x2,
                                                const short* __restrict__ keys,
                                                const int* __restrict__ cnt,
                                                const int* __restrict__ toklist,
                                                short* __restrict__ hbuf) {
  const int e = blockIdx.y;
  const int n = cnt[e];
  const int t0 = blockIdx.x << 6;
  if (t0 >= n) return;
  __shared__ int stok[64];
  __shared__ __align__(16) short lA[64 * 36];
  __shared__ __align__(16) short lB[128 * 36];
  const int tid = threadIdx.x;
  if (tid < 64) {
    int idx = t0 + tid;
    stok[tid] = toklist[e * CAP + (idx < n ? idx : n - 1)];
  }
  __syncthreads();
  const int w = tid >> 6, lane = tid & 63, cl = lane & 15, g = lane >> 4;
  const int ar = tid >> 2, ak = (tid & 3) << 3;
  const int bkr = tid >> 3, bc0 = (tid & 7) << 4;
  const short* kbase = keys + ((size_t)e << 17);
  f32x4 acc[8] = {};
  for (int kt = 0; kt < 1024; kt += 32) {
    if (kt) __syncthreads();
    *(s16x8*)&lA[ar * 36 + ak] = *(const s16x8*)&x2[stok[ar] * 1024 + kt + ak];
    {
      s16x8 b0 = *(const s16x8*)&kbase[(kt + bkr) * 128 + bc0];
      s16x8 b1 = *(const s16x8*)&kbase[(kt + bkr) * 128 + bc0 + 8];
#pragma unroll
      for (int i2 = 0; i2 < 8; ++i2) {
        lB[(bc0 + i2) * 36 + bkr] = b0[i2];
        lB[(bc0 + 8 + i2) * 36 + bkr] = b1[i2];
      }
    }
    __syncthreads();
    bf16x8 a = *(const bf16x8*)&lA[(w * 16 + cl) * 36 + g * 8];
#pragma unroll
    for (int nt = 0; nt < 8; ++nt) {
      bf16x8 bfr = *(const bf16x8*)&lB[(nt * 16 + cl) * 36 + g * 8];
      acc[nt] = mfma16(a, bfr, acc[nt]);
    }
  }
#pragma unroll
  for (int nt = 0; nt < 8; ++nt)
#pragma unroll
    for (int r = 0; r < 4; ++r) {
      int lrow = w * 16 + g * 4 + r;
      if (t0 + lrow < n)
        hbuf[(size_t)(e * CAP + t0 + lrow) * 128 + nt * 16 + cl] =
            f2b(fmaxf(acc[nt][r], 0.f));
    }
}

// ---------------------------------------------------------------- MoE down: out += gate * (h @ vals[e])
// M=64 slots, N=1024, K=128
__global__ __launch_bounds__(256) void moe_down_k(const short* __restrict__ hbuf,
                                                  const short* __restrict__ vals,
                                                  const int* __restrict__ cnt,
                                                  const int* __restrict__ toklist,
                                                  const float* __restrict__ gatelist,
                                                  float* __restrict__ out) {
  const int e = blockIdx.y;
  const int n = cnt[e];
  const int t0 = blockIdx.x << 6;
  if (t0 >= n) return;
  __shared__ int stok[64];
  __shared__ float sgate[64];
  __shared__ __align__(16) short lA[64 * 132];
  __shared__ __align__(16) short lB[64 * 132];
  const int tid = threadIdx.x;
  if (tid < 64) {
    int idx = t0 + tid;
    int ci = idx < n ? idx : n - 1;
    stok[tid] = toklist[e * CAP + ci];
    sgate[tid] = gatelist[e * CAP + ci];
  }
  {
    int ar = tid >> 2, ac0 = (tid & 3) << 3;
    const short* hr = &hbuf[(size_t)(e * CAP + t0 + ar) * 128];
#pragma unroll
    for (int u = 0; u < 4; ++u)
      *(s16x8*)&lA[ar * 132 + ac0 + u * 32] = *(const s16x8*)&hr[ac0 + u * 32];
  }
  const int w = tid >> 6, lane = tid & 63, cl = lane & 15, g = lane >> 4;
  const short* vbase = vals + ((size_t)e << 17);
  const int bkr = tid >> 1, bc0 = (tid & 1) << 5;
  __syncthreads();
  bf16x8 afr[4];
#pragma unroll
  for (int ks = 0; ks < 4; ++ks)
    afr[ks] = *(const bf16x8*)&lA[(w * 16 + cl) * 132 + ks * 32 + g * 8];
  float gates[4];
  int stokr[4];
  bool valid[4];
#pragma unroll
  for (int r = 0; r < 4; ++r) {
    int lrow = w * 16 + g * 4 + r;
    gates[r] = sgate[lrow];
    stokr[r] = stok[lrow];
    valid[r] = (t0 + lrow) < n;
  }
  for (int nc = 0; nc < 16; ++nc) {
    __syncthreads();
#pragma unroll
    for (int u = 0; u < 4; ++u) {
      s16x8 bv = *(const s16x8*)&vbase[bkr * 1024 + nc * 64 + bc0 + u * 8];
#pragma unroll
      for (int i2 = 0; i2 < 8; ++i2) lB[(bc0 + u * 8 + i2) * 132 + bkr] = bv[i2];
    }
    __syncthreads();
    f32x4 acc[4] = {};
#pragma unroll
    for (int ks = 0; ks < 4; ++ks)
#pragma unroll
      for (int nt = 0; nt < 4; ++nt) {
        bf16x8 bfr = *(const bf16x8*)&lB[(nt * 16 + cl) * 132 + ks * 32 + g * 8];
        acc[nt] = mfma16(afr[ks], bfr, acc[nt]);
      }
#pragma unroll
    for (int nt = 0; nt < 4; ++nt)
#pragma unroll
      for (int r = 0; r < 4; ++r)
        if (valid[r])
          atomicAdd(&out[stokr[r] * 1024 + nc * 64 + nt * 16 + cl],
                    gates[r] * acc[nt][r]);
  }
}

// ---------------------------------------------------------------- launch
extern "C" void kernel_launch(void* const* d_in, const int* in_sizes, int n_in,
                              void* d_out, int out_size, void* d_ws, size_t ws_size,
                              hipStream_t stream) {
  const float* src = (const float*)d_in[0];
  const float* ln1g = (const float*)d_in[6];
  const float* ln1b = (const float*)d_in[7];
  const float* ln2g = (const float*)d_in[8];
  const float* ln2b = (const float*)d_in[9];
  const float* selw = (const float*)d_in[10];

  char* ws = (char*)d_ws;
  short* x2a = (short*)(ws + (size_t)0);           // 4MB bf16 LN1 out
  short* pos = (short*)(ws + ((size_t)4 << 20));   // 4MB (dead after P-proj; reused below)
  short* P = (short*)(ws + ((size_t)8 << 20));     // 4MB
  short* q = (short*)(ws + ((size_t)12 << 20));    // 4MB (dead after attn; hbuf reuse)
  short* k = (short*)(ws + ((size_t)16 << 20));    // 4MB
  short* v = (short*)(ws + ((size_t)20 << 20));    // 4MB
  short* ao = (short*)(ws + ((size_t)24 << 20));   // 4MB (dead after Wo-proj)
  short* x2b = (short*)(ws + ((size_t)28 << 20));  // 4MB bf16 LN2 out
  float* x = (float*)(ws + ((size_t)32 << 20));    // 8MB f32 residual1
  float* topv = (float*)(ws + ((size_t)40 << 20));
  int* topi = (int*)(ws + ((size_t)40 << 20) + (32 << 10));
  short* cWq = (short*)(ws + ((size_t)41 << 20));  // 2MB each
  short* cWk = (short*)(ws + ((size_t)43 << 20));
  short* cWv = (short*)(ws + ((size_t)45 << 20));
  short* cWo = (short*)(ws + ((size_t)47 << 20));
  short* cWp = (short*)(ws + ((size_t)49 << 20));
  short* cKeys = (short*)(ws + ((size_t)51 << 20));  // 8MB
  short* cVals = (short*)(ws + ((size_t)59 << 20));  // 8MB
  // MoE scratch reusing dead regions:
  short* hbuf = q;                                      // 16MB over q,k,v,ao (12..28MB)
  int* cnt = (int*)(ws + ((size_t)4 << 20));            // over pos (dead by then)
  int* toklist = (int*)(ws + ((size_t)4 << 20) + (4 << 10));
  float* gatelist = (float*)(ws + ((size_t)4 << 20) + (512 << 10));

  conv_k<<<512, 256, 0, stream>>>((const float*)d_in[1], cWq, 1048576);
  conv_k<<<512, 256, 0, stream>>>((const float*)d_in[2], cWk, 1048576);
  conv_k<<<512, 256, 0, stream>>>((const float*)d_in[3], cWv, 1048576);
  conv_k<<<512, 256, 0, stream>>>((const float*)d_in[4], cWo, 1048576);
  conv_k<<<512, 256, 0, stream>>>((const float*)d_in[5], cWp, 1048576);
  conv_k<<<1024, 256, 0, stream>>>((const float*)d_in[11], cKeys, 4194304);
  conv_k<<<1024, 256, 0, stream>>>((const float*)d_in[12], cVals, 4194304);

  dim3 gg(16, 32);  // (N/64, M/64)
  pos_k<<<2048, 256, 0, stream>>>(pos);
  ln_k<<<2048, 256, 0, stream>>>(src, ln1g, ln1b, x2a);
  gemm_k<1><<<gg, 256, 0, stream>>>(x2a, cWq, q, nullptr);
  gemm_k<1><<<gg, 256, 0, stream>>>(x2a, cWk, k, nullptr);
  gemm_k<1><<<gg, 256, 0, stream>>>(x2a, cWv, v, nullptr);
  gemm_k<0><<<gg, 256, 0, stream>>>(pos, cWp, P, nullptr);
  attn_k<<<512, 256, 0, stream>>>(q, k, v, P, ao);
  gemm_k<2><<<gg, 256, 0, stream>>>(ao, cWo, x, src);
  ln_k<<<2048, 256, 0, stream>>>(x, ln2g, ln2b, x2b);
  gate_k<<<2048, 256, 0, stream>>>(x, ln2g, ln2b, selw, topv, topi);
  zero_k<<<1, 32, 0, stream>>>(cnt);
  bucket_k<<<8, 256, 0, stream>>>(topi, topv, cnt, toklist, gatelist);
  cp_k<<<2048, 256, 0, stream>>>(x, (float*)d_out);
  moe_up_k<<<dim3(32, 32), 256, 0, stream>>>(x2b, cKeys, cnt, toklist, hbuf);
  moe_down_k<<<dim3(32, 32), 256, 0, stream>>>(hbuf, cVals, cnt, toklist, gatelist,
                                               (float*)d_out);
}